// Round 5
// baseline (197.299 us; speedup 1.0000x reference)
//
#include <hip/hip_runtime.h>

// LTC cell: B=1024, I=128, N=256, 6 unfolds. Round 5.
// Round-4 fused structure (block = 4 batches x all 256 n, grid 256) plus:
//  - weights compressed: (-A,B) f32 pairs + (W, W*erev) f16x4 -> 24 B / 2 terms
//    (cuts L2 stream from 268 to 201 MB/step; f16 on W only, arg stays f32)
//  - __launch_bounds__(1024,4): VGPR cap 128 (was 44) so the scheduler can
//    keep ~16 independent exp2/rcp chains in flight per wave
//  - j-pair loop: 16 terms per body, loads clustered at top, unroll 4

#define LOG2E 1.44269504088896340f

constexpr int Bn = 1024;
constexpr int In = 128;
constexpr int Nn = 256;
constexpr int UNFOLDS = 6;

typedef _Float16 h4 __attribute__((ext_vector_type(4)));

#if __has_builtin(__builtin_amdgcn_exp2f)
#define EXP2F(x) __builtin_amdgcn_exp2f(x)
#else
#define EXP2F(x) __exp2f(x)
#endif
#if __has_builtin(__builtin_amdgcn_rcpf)
#define RCPF(x) __builtin_amdgcn_rcpf(x)
#else
#define RCPF(x) (1.0f / (x))
#endif

// ---------------------------------------------------------------------------
// Pack: pair-of-i layout, n fastest (coalesced across lanes).
//   PrecAB[j*256+n] = {-A(2j,n), -A(2j+1,n), B(2j,n), B(2j+1,n)}   (f32x4)
//   PrecW [j*256+n] = {W(2j), W(2j+1), We(2j), We(2j+1)}           (f16x4)
// with A = sigma*log2e, B = sigma*mu*log2e, We = W*erev.
// sigmoid(sigma*(v-mu)) = 1/(1 + exp2(fma(-A, v, B))).
// ---------------------------------------------------------------------------
__global__ __launch_bounds__(256) void pack_kernel(
    const float* __restrict__ mu, const float* __restrict__ sigma,
    const float* __restrict__ W, const float* __restrict__ erev,
    const float* __restrict__ smu, const float* __restrict__ ssigma,
    const float* __restrict__ sW, const float* __restrict__ serev,
    float4* __restrict__ PrecAB, h4* __restrict__ PrecW,
    float4* __restrict__ PsenAB, h4* __restrict__ PsenW) {
    int idx = blockIdx.x * 256 + threadIdx.x;
    if (idx < 128 * Nn) {
        int n = idx & 255, i0 = (idx >> 8) * 2;
        int a = i0 * Nn + n, b = a + Nn;
        float s0 = sigma[a], s1 = sigma[b], m0 = mu[a], m1 = mu[b];
        PrecAB[idx] = make_float4(-s0 * LOG2E, -s1 * LOG2E,
                                  s0 * m0 * LOG2E, s1 * m1 * LOG2E);
        float w0 = W[a], w1 = W[b];
        h4 h;
        h[0] = (_Float16)w0;
        h[1] = (_Float16)w1;
        h[2] = (_Float16)(w0 * erev[a]);
        h[3] = (_Float16)(w1 * erev[b]);
        PrecW[idx] = h;
        return;
    }
    int jdx = idx - 128 * Nn;
    if (jdx < 64 * Nn) {
        int n = jdx & 255, i0 = (jdx >> 8) * 2;
        int a = i0 * Nn + n, b = a + Nn;
        float s0 = ssigma[a], s1 = ssigma[b], m0 = smu[a], m1 = smu[b];
        PsenAB[jdx] = make_float4(-s0 * LOG2E, -s1 * LOG2E,
                                  s0 * m0 * LOG2E, s1 * m1 * LOG2E);
        float w0 = sW[a], w1 = sW[b];
        h4 h;
        h[0] = (_Float16)w0;
        h[1] = (_Float16)w1;
        h[2] = (_Float16)(w0 * serev[a]);
        h[3] = (_Float16)(w1 * serev[b]);
        PsenW[jdx] = h;
    }
}

// 4 sigmoid terms (one i, 4 batches) -> accumulate into num[4]/den[4].
#define TERM4(nA, Bc, Wv, Ev, v4)                                   \
    {                                                               \
        float r0 = RCPF(1.f + EXP2F(fmaf((nA), (v4).x, (Bc))));     \
        float r1 = RCPF(1.f + EXP2F(fmaf((nA), (v4).y, (Bc))));     \
        float r2 = RCPF(1.f + EXP2F(fmaf((nA), (v4).z, (Bc))));     \
        float r3 = RCPF(1.f + EXP2F(fmaf((nA), (v4).w, (Bc))));     \
        den[0] += (Wv)*r0; den[1] += (Wv)*r1;                       \
        den[2] += (Wv)*r2; den[3] += (Wv)*r3;                       \
        num[0] += (Ev)*r0; num[1] += (Ev)*r1;                       \
        num[2] += (Ev)*r2; num[3] += (Ev)*r3;                       \
    }

// ---------------------------------------------------------------------------
// Fused LTC kernel: sensory + 6 unfolds. Grid 256 x 1024 thr.
// thread = (n = tid&255, ih = tid>>8); ih is both i-slice and output batch.
// ---------------------------------------------------------------------------
__global__ __launch_bounds__(1024, 4) void ltc_fused_kernel(
    const float* __restrict__ inputs, const float* __restrict__ state,
    const float* __restrict__ input_w, const float* __restrict__ input_b,
    const float4* __restrict__ PsenAB, const h4* __restrict__ PsenW,
    const float4* __restrict__ PrecAB, const h4* __restrict__ PrecW,
    const float* __restrict__ vleak, const float* __restrict__ gleak,
    const float* __restrict__ cmt, float* __restrict__ out) {
    __shared__ float4 vt[Nn];            // [i] -> 4 batches, 4 KB
    __shared__ float4 xs[In];            // [i] -> 4 batches, 2 KB
    __shared__ float2 part[4][4][Nn];    // [ih][bb][n], 32 KB

    const int tid = threadIdx.x;
    const int b0 = blockIdx.x * 4;
    const int n = tid & 255;
    const int ih = tid >> 8;

    float vp = state[(b0 + ih) * Nn + n];
    ((float*)vt)[n * 4 + ih] = vp;
    if (tid < 512) {
        int i = tid & 127, bb = tid >> 7;
        ((float*)xs)[i * 4 + bb] =
            inputs[(b0 + bb) * In + i] * input_w[i] + input_b[i];
    }
    const float g = gleak[n], c = cmt[n];
    const float gvl = g * vleak[n];
    __syncthreads();

    // ---- sensory (i-pairs j: 16 per ih) ----
    float sens_n, sens_d;
    {
        float num[4] = {0.f, 0.f, 0.f, 0.f};
        float den[4] = {0.f, 0.f, 0.f, 0.f};
        const float4* __restrict__ pAB = PsenAB + n;
        const h4* __restrict__ pW = PsenW + n;
        const int j0 = ih * 16;
#pragma unroll 4
        for (int j = j0; j < j0 + 16; ++j) {
            float4 ab = pAB[j * Nn];   // coalesced dwordx4
            h4 hw = pW[j * Nn];        // coalesced dwordx2
            float4 va = xs[2 * j];     // b128 broadcast
            float4 vb = xs[2 * j + 1];
            float W0 = (float)hw[0], W1 = (float)hw[1];
            float E0 = (float)hw[2], E1 = (float)hw[3];
            TERM4(ab.x, ab.z, W0, E0, va);
            TERM4(ab.y, ab.w, W1, E1, vb);
        }
#pragma unroll
        for (int bb = 0; bb < 4; ++bb)
            part[ih][bb][n] = make_float2(num[bb], den[bb]);
        __syncthreads();
        float wn = 0.f, wd = 0.f;
#pragma unroll
        for (int s = 0; s < 4; ++s) {
            float2 v = part[s][ih][n];
            wn += v.x;
            wd += v.y;
        }
        sens_n = wn;
        sens_d = wd;
    }

    // ---- 6 unfolds (i-pairs j: 32 per ih) ----
    const float4* __restrict__ pAB = PrecAB + n;
    const h4* __restrict__ pW = PrecW + n;
    for (int s = 0; s < UNFOLDS; ++s) {
        __syncthreads();  // vt from prev step visible; part free for reuse
        float num[4] = {0.f, 0.f, 0.f, 0.f};
        float den[4] = {0.f, 0.f, 0.f, 0.f};
        const int j0 = ih * 32;
#pragma unroll 4
        for (int j = j0; j < j0 + 32; ++j) {
            float4 ab = pAB[j * Nn];   // coalesced dwordx4 (L2 stream)
            h4 hw = pW[j * Nn];        // coalesced dwordx2
            float4 va = vt[2 * j];     // b128 broadcast
            float4 vb = vt[2 * j + 1];
            float W0 = (float)hw[0], W1 = (float)hw[1];
            float E0 = (float)hw[2], E1 = (float)hw[3];
            TERM4(ab.x, ab.z, W0, E0, va);
            TERM4(ab.y, ab.w, W1, E1, vb);
        }
#pragma unroll
        for (int bb = 0; bb < 4; ++bb)
            part[ih][bb][n] = make_float2(num[bb], den[bb]);
        __syncthreads();
        float wn = sens_n, wd = sens_d;
#pragma unroll
        for (int s2 = 0; s2 < 4; ++s2) {
            float2 v = part[s2][ih][n];
            wn += v.x;
            wd += v.y;
        }
        float res = (c * vp + gvl + wn) * RCPF(c + g + wd);
        vp = res;
        if (s == UNFOLDS - 1)
            out[(b0 + ih) * Nn + n] = res;
        else
            ((float*)vt)[n * 4 + ih] = res;
    }
}

// ---------------------------------------------------------------------------
extern "C" void kernel_launch(void* const* d_in, const int* in_sizes, int n_in,
                              void* d_out, int out_size, void* d_ws, size_t ws_size,
                              hipStream_t stream) {
    const float* inputs   = (const float*)d_in[0];
    const float* state    = (const float*)d_in[1];
    const float* input_w  = (const float*)d_in[2];
    const float* input_b  = (const float*)d_in[3];
    const float* smu      = (const float*)d_in[4];
    const float* ssigma   = (const float*)d_in[5];
    const float* sW       = (const float*)d_in[6];
    const float* serev    = (const float*)d_in[7];
    const float* mu       = (const float*)d_in[8];
    const float* sigma    = (const float*)d_in[9];
    const float* W        = (const float*)d_in[10];
    const float* erev     = (const float*)d_in[11];
    const float* vleak    = (const float*)d_in[12];
    const float* gleak    = (const float*)d_in[13];
    const float* cmt      = (const float*)d_in[14];
    float* out = (float*)d_out;

    // Workspace: PrecAB 512K | PrecW 256K | PsenAB 256K | PsenW 128K
    char* ws = (char*)d_ws;
    float4* PrecAB = (float4*)ws;
    h4*     PrecW  = (h4*)(ws + (512u << 10));
    float4* PsenAB = (float4*)(ws + (768u << 10));
    h4*     PsenW  = (h4*)(ws + (1024u << 10));

    pack_kernel<<<192, 256, 0, stream>>>(
        mu, sigma, W, erev, smu, ssigma, sW, serev,
        PrecAB, PrecW, PsenAB, PsenW);

    ltc_fused_kernel<<<Bn / 4, 1024, 0, stream>>>(
        inputs, state, input_w, input_b, PsenAB, PsenW, PrecAB, PrecW,
        vleak, gleak, cmt, out);
}

// Round 6
// 193.340 us; speedup vs baseline: 1.0205x; 1.0205x over previous
//
#include <hip/hip_runtime.h>

// LTC cell: B=1024, I=128, N=256, 6 unfolds. Round 6.
// Fused recurrence (round-4 structure) with:
//  - bb=2 batches/block, grid 512 -> 2 blocks/CU -> 8 waves/SIMD (occupancy
//    44% -> ~90%) to hide trans-pipe dependency stalls
//  - weights packed 4 x f16 = 8 B/(i,n): {-A, B, W, W*erev}; consumed with
//    fmaf((float)h, v, (float)h) -> v_fma_mix_f32 (no cvt, full rate), so
//    per-CU VMEM stays at round-4's 1 MB/step despite 2 blocks/CU.
// Issue floor ~48 cyc per wave-i (8 full-rate + 4 trans on shared pipe).

#define LOG2E 1.44269504088896340f

constexpr int Bn = 1024;
constexpr int In = 128;
constexpr int Nn = 256;
constexpr int UNFOLDS = 6;

typedef _Float16 h4 __attribute__((ext_vector_type(4)));

#if __has_builtin(__builtin_amdgcn_exp2f)
#define EXP2F(x) __builtin_amdgcn_exp2f(x)
#else
#define EXP2F(x) __exp2f(x)
#endif
#if __has_builtin(__builtin_amdgcn_rcpf)
#define RCPF(x) __builtin_amdgcn_rcpf(x)
#else
#define RCPF(x) (1.0f / (x))
#endif

// ---------------------------------------------------------------------------
// Pack: PrecH[i*N+n] = f16x4 {-A, B, W, W*erev}, A=sigma*log2e, B=sigma*mu*log2e.
// sigmoid(sigma*(v-mu)) = 1/(1 + exp2(fma(-A, v, B))). Same for PsenH.
// ---------------------------------------------------------------------------
__global__ __launch_bounds__(256) void pack_kernel(
    const float* __restrict__ mu, const float* __restrict__ sigma,
    const float* __restrict__ W, const float* __restrict__ erev,
    const float* __restrict__ smu, const float* __restrict__ ssigma,
    const float* __restrict__ sW, const float* __restrict__ serev,
    h4* __restrict__ PrecH, h4* __restrict__ PsenH) {
    int idx = blockIdx.x * 256 + threadIdx.x;
    if (idx < Nn * Nn) {
        float s = sigma[idx], m = mu[idx], w = W[idx], e = erev[idx];
        h4 h;
        h[0] = (_Float16)(-s * LOG2E);
        h[1] = (_Float16)(s * m * LOG2E);
        h[2] = (_Float16)w;
        h[3] = (_Float16)(w * e);
        PrecH[idx] = h;
        return;
    }
    int j = idx - Nn * Nn;
    if (j < In * Nn) {
        float s = ssigma[j], m = smu[j], w = sW[j], e = serev[j];
        h4 h;
        h[0] = (_Float16)(-s * LOG2E);
        h[1] = (_Float16)(s * m * LOG2E);
        h[2] = (_Float16)w;
        h[3] = (_Float16)(w * e);
        PsenH[j] = h;
    }
}

// ---------------------------------------------------------------------------
// Fused LTC kernel: sensory + 6 unfolds.
// Grid 512 x 1024 thr. Block owns 2 batches x all 256 n.
// thread = (n = tid&255, ih = tid>>8 in 0..3). ih = i-slice; threads with
// ih < 2 also own the (bb=ih, n) output.
// ---------------------------------------------------------------------------
__global__ __launch_bounds__(1024, 8) void ltc_fused_kernel(
    const float* __restrict__ inputs, const float* __restrict__ state,
    const float* __restrict__ input_w, const float* __restrict__ input_b,
    const h4* __restrict__ PsenH, const h4* __restrict__ PrecH,
    const float* __restrict__ vleak, const float* __restrict__ gleak,
    const float* __restrict__ cmt, float* __restrict__ out) {
    __shared__ float2 vt[Nn];            // [i] -> 2 batches, 2 KB
    __shared__ float2 xs[In];            // [i] -> 2 batches, 1 KB
    __shared__ float2 part[4][2][Nn];    // [ih][bb][n], 16 KB

    const int tid = threadIdx.x;
    const int b0 = blockIdx.x * 2;
    const int n = tid & 255;
    const int ih = tid >> 8;

    float vp = 0.f, g = 0.f, c = 0.f, gvl = 0.f;
    if (ih < 2) {
        vp = state[(b0 + ih) * Nn + n];        // coalesced
        ((float*)vt)[n * 2 + ih] = vp;
        g = gleak[n];
        c = cmt[n];
        gvl = g * vleak[n];
    }
    if (tid < 256) {                           // xs: 128 i x 2 bb
        int i = tid & 127, bb = tid >> 7;
        ((float*)xs)[i * 2 + bb] =
            inputs[(b0 + bb) * In + i] * input_w[i] + input_b[i];
    }
    __syncthreads();

    // ---- sensory: slice of 32 i per ih ----
    float sens_n = 0.f, sens_d = 0.f;
    {
        float num0 = 0.f, num1 = 0.f, den0 = 0.f, den1 = 0.f;
        const h4* __restrict__ p = PsenH + n;
        const int j0 = ih * 32;
#pragma unroll 8
        for (int i = j0; i < j0 + 32; ++i) {
            h4 hw = p[i * Nn];       // coalesced dwordx2
            float2 v2 = xs[i];       // ds_read_b64 broadcast
            float t0 = fmaf((float)hw[0], v2.x, (float)hw[1]);  // fma_mix
            float t1 = fmaf((float)hw[0], v2.y, (float)hw[1]);
            float r0 = RCPF(1.f + EXP2F(t0));
            float r1 = RCPF(1.f + EXP2F(t1));
            den0 = fmaf((float)hw[2], r0, den0);
            num0 = fmaf((float)hw[3], r0, num0);
            den1 = fmaf((float)hw[2], r1, den1);
            num1 = fmaf((float)hw[3], r1, num1);
        }
        part[ih][0][n] = make_float2(num0, den0);
        part[ih][1][n] = make_float2(num1, den1);
        __syncthreads();
        if (ih < 2) {
#pragma unroll
            for (int s = 0; s < 4; ++s) {
                float2 v = part[s][ih][n];
                sens_n += v.x;
                sens_d += v.y;
            }
        }
    }

    // ---- 6 unfolds: slice of 64 i per ih ----
    const h4* __restrict__ p = PrecH + n;
    for (int s = 0; s < UNFOLDS; ++s) {
        __syncthreads();  // vt updated & part free for reuse
        float num0 = 0.f, num1 = 0.f, den0 = 0.f, den1 = 0.f;
        const int j0 = ih * 64;
#pragma unroll 8
        for (int i = j0; i < j0 + 64; ++i) {
            h4 hw = p[i * Nn];       // coalesced dwordx2 (L2-resident stream)
            float2 v2 = vt[i];       // ds_read_b64 broadcast
            float t0 = fmaf((float)hw[0], v2.x, (float)hw[1]);  // fma_mix
            float t1 = fmaf((float)hw[0], v2.y, (float)hw[1]);
            float r0 = RCPF(1.f + EXP2F(t0));
            float r1 = RCPF(1.f + EXP2F(t1));
            den0 = fmaf((float)hw[2], r0, den0);
            num0 = fmaf((float)hw[3], r0, num0);
            den1 = fmaf((float)hw[2], r1, den1);
            num1 = fmaf((float)hw[3], r1, num1);
        }
        part[ih][0][n] = make_float2(num0, den0);
        part[ih][1][n] = make_float2(num1, den1);
        __syncthreads();
        if (ih < 2) {
            float wn = sens_n, wd = sens_d;
#pragma unroll
            for (int s2 = 0; s2 < 4; ++s2) {
                float2 v = part[s2][ih][n];
                wn += v.x;
                wd += v.y;
            }
            float res = (fmaf(c, vp, gvl) + wn) * RCPF(c + g + wd);
            vp = res;
            if (s == UNFOLDS - 1)
                out[(b0 + ih) * Nn + n] = res;   // coalesced
            else
                ((float*)vt)[n * 2 + ih] = res;
        }
    }
}

// ---------------------------------------------------------------------------
extern "C" void kernel_launch(void* const* d_in, const int* in_sizes, int n_in,
                              void* d_out, int out_size, void* d_ws, size_t ws_size,
                              hipStream_t stream) {
    const float* inputs   = (const float*)d_in[0];
    const float* state    = (const float*)d_in[1];
    const float* input_w  = (const float*)d_in[2];
    const float* input_b  = (const float*)d_in[3];
    const float* smu      = (const float*)d_in[4];
    const float* ssigma   = (const float*)d_in[5];
    const float* sW       = (const float*)d_in[6];
    const float* serev    = (const float*)d_in[7];
    const float* mu       = (const float*)d_in[8];
    const float* sigma    = (const float*)d_in[9];
    const float* W        = (const float*)d_in[10];
    const float* erev     = (const float*)d_in[11];
    const float* vleak    = (const float*)d_in[12];
    const float* gleak    = (const float*)d_in[13];
    const float* cmt      = (const float*)d_in[14];
    float* out = (float*)d_out;

    // Workspace: PrecH 512 KiB | PsenH 256 KiB
    char* ws = (char*)d_ws;
    h4* PrecH = (h4*)ws;
    h4* PsenH = (h4*)(ws + (512u << 10));

    pack_kernel<<<(Nn * Nn + In * Nn + 255) / 256, 256, 0, stream>>>(
        mu, sigma, W, erev, smu, ssigma, sW, serev, PrecH, PsenH);

    ltc_fused_kernel<<<Bn / 2, 1024, 0, stream>>>(
        inputs, state, input_w, input_b, PsenH, PrecH, vleak, gleak, cmt, out);
}